// Round 1
// baseline (227.380 us; speedup 1.0000x reference)
//
#include <hip/hip_runtime.h>
#include <stdint.h>

#define BATCH 8
#define SEQ   2048
#define DIM   512

typedef __attribute__((ext_vector_type(8)))  short short8;    // 8 bf16 (4 VGPRs)
typedef __attribute__((ext_vector_type(16))) float floatx16;  // 32x32 C/D frag

static __device__ __forceinline__ unsigned short f32_bf16(float f) {
  unsigned u = __builtin_bit_cast(unsigned, f);
  u += 0x7FFFu + ((u >> 16) & 1u);          // round-to-nearest-even
  return (unsigned short)(u >> 16);
}
static __device__ __forceinline__ short8 ld_frag8(const unsigned short* p) {
  return __builtin_bit_cast(short8, *reinterpret_cast<const uint4*>(p));
}
static __device__ __forceinline__ void gld_lds16(const unsigned short* g, unsigned short* l) {
  __builtin_amdgcn_global_load_lds((const __attribute__((address_space(1))) unsigned int*)g,
                                   (__attribute__((address_space(3))) unsigned int*)l, 16, 0, 0);
}
static __device__ __forceinline__ float bf_lo(unsigned u) {
  return __builtin_bit_cast(float, u << 16);
}
static __device__ __forceinline__ float bf_hi(unsigned u) {
  return __builtin_bit_cast(float, u & 0xFFFF0000u);
}

// ---------------- prep: x -> xn (bf16 x-hat, row-major) and xt (bf16 x^T, [b][d][j]) --------
// grid 512 = 8 batches (XCD-pinned &7) x 64 j-tiles of 32 rows ; 256 threads
__global__ __launch_bounds__(256) void prep_kernel(const float* __restrict__ x,
                                                   unsigned short* __restrict__ xn,
                                                   unsigned short* __restrict__ xt) {
  const int b   = blockIdx.x & 7;
  const int jt  = blockIdx.x >> 3;     // 0..63
  const int t   = threadIdx.x;
  const int row = t >> 3;              // 0..31
  const int oct = t & 7;               // 0..7

  __shared__ unsigned short xs[512 * 34];   // [d][j] bf16, pitch 34 u16 (34.8 KB)

  const long rowg = ((long)b * SEQ + jt * 32 + row) * DIM;
  const float* xp = x + rowg;

  float4 v[16];
#pragma unroll
  for (int k = 0; k < 16; ++k)
    v[k] = *reinterpret_cast<const float4*>(xp + k * 32 + oct * 4);

  float acc = 0.f;
#pragma unroll
  for (int k = 0; k < 16; ++k)
    acc += v[k].x*v[k].x + v[k].y*v[k].y + v[k].z*v[k].z + v[k].w*v[k].w;
  acc += __shfl_xor(acc, 1);
  acc += __shfl_xor(acc, 2);
  acc += __shfl_xor(acc, 4);
  const float sc = 1.f / (sqrtf(acc) + 1e-12f);

  // xn straight from registers
  unsigned short* xnp = xn + rowg + oct * 4;
#pragma unroll
  for (int k = 0; k < 16; ++k) {
    ushort4 pk;
    pk.x = f32_bf16(v[k].x * sc); pk.y = f32_bf16(v[k].y * sc);
    pk.z = f32_bf16(v[k].z * sc); pk.w = f32_bf16(v[k].w * sc);
    *reinterpret_cast<ushort4*>(xnp + k * 32) = pk;
  }

  // LDS transpose staging
#pragma unroll
  for (int k = 0; k < 16; ++k) {
    const int d = k * 32 + oct * 4;
    xs[(d + 0) * 34 + row] = f32_bf16(v[k].x);
    xs[(d + 1) * 34 + row] = f32_bf16(v[k].y);
    xs[(d + 2) * 34 + row] = f32_bf16(v[k].z);
    xs[(d + 3) * 34 + row] = f32_bf16(v[k].w);
  }
  __syncthreads();

  // xt: 64B segments per d-row; jt-adjacent blocks (same XCD) complete 128B lines in L2
  unsigned short* xtb = xt + (long)b * DIM * SEQ + jt * 32;
  const int wv = t >> 6, li = t & 63, dsub = li >> 2, jc = li & 3;
#pragma unroll
  for (int it = 0; it < 8; ++it) {
    const int d = it * 64 + wv * 16 + dsub;
    const unsigned* bp = reinterpret_cast<const unsigned*>(&xs[d * 34]);
    uint4 o;
    o.x = bp[jc * 4 + 0]; o.y = bp[jc * 4 + 1];
    o.z = bp[jc * 4 + 2]; o.w = bp[jc * 4 + 3];
    *reinterpret_cast<uint4*>(xtb + (long)d * SEQ + jc * 8) = o;
  }
}

// ---------------- fused flash-style kernel: S -> P=exp(S^2-1) -> O += P.X, l += rowsum(P) ---
// grid 256 = 8 batches (XCD-pinned) x 32 i-tiles of 64 rows ; 512 threads = 8 waves ; 1 blk/CU
// LDS: sQ 64KB (xn_i, XOR-swizzled) + sP 64KB (bf16 P j-tile, XOR-swizzled) = 128KB
// Per j-tile (512 cols): S phase (A=sQ LDS, B=xn direct L2, each B-frag unique per wave),
// exp in-register, sP write, PV phase (A=sP LDS, B=xt rows direct L2, unique per wave),
// fused bf16-exact row-sum from sP. Only 2 barriers per j-tile.
__global__ __launch_bounds__(512, 2) void fused_kernel(const unsigned short* __restrict__ xn,
                                                       const unsigned short* __restrict__ xt,
                                                       float* __restrict__ out) {
  const int b  = blockIdx.x & 7;
  const int i0 = (blockIdx.x >> 3) * 64;
  const int tid  = threadIdx.x;
  const int w    = tid >> 6;        // 0..7
  const int lane = tid & 63;
  const int ln   = lane & 31;
  const int half = lane >> 5;

  __shared__ __align__(16) unsigned short sQ[64 * 512];   // 64 KB
  __shared__ __align__(16) unsigned short sP[64 * 512];   // 64 KB
  __shared__ float sL[64];

  const unsigned short* xb  = xn + (size_t)b * SEQ * DIM;
  const unsigned short* xtb = xt + (size_t)b * DIM * SEQ;

  // ---- stage sQ: linear LDS dest + inverse-swizzled global source (rule #21) ----
  // each wave stages one full row per k-iter: row = k*8 + w, 64 lanes x 16B = 1024B row
#pragma unroll
  for (int k = 0; k < 8; ++k) {
    const int u   = tid + k * 512;
    const int row = u >> 6;                 // uniform per wave per k
    const int c   = u & 63;                 // dest granule in row
    const int sub = (c & 7) ^ ((row ^ (row >> 3)) & 7);
    gld_lds16(xb + (size_t)(i0 + row) * DIM + (c >> 3) * 64 + sub * 8, sQ + u * 8);
  }

  floatx16 acc_o[2][2];
#pragma unroll
  for (int it = 0; it < 2; ++it)
#pragma unroll
    for (int dt = 0; dt < 2; ++dt)
#pragma unroll
      for (int e = 0; e < 16; ++e) acc_o[it][dt][e] = 0.f;

  float lsum = 0.f;
  const int lrow = tid >> 3;        // row this thread helps row-sum (0..63)
  const int lseg = tid & 7;

  __syncthreads();                  // sQ staged (vmcnt drained by barrier)

  for (int jt = 0; jt < 4; ++jt) {
    const int j0 = jt * 512;

    // ---------- S phase: per-wave [64 i][64 j] tile at j-strip w*64, K=512 ----------
    floatx16 acc_s[2][2];
#pragma unroll
    for (int it = 0; it < 2; ++it)
#pragma unroll
      for (int j2 = 0; j2 < 2; ++j2)
#pragma unroll
        for (int e = 0; e < 16; ++e) acc_s[it][j2][e] = 0.f;

    const unsigned short* Bg = xb + (size_t)(j0 + w * 64) * DIM;
#pragma unroll
    for (int kc = 0; kc < 8; ++kc) {
#pragma unroll
      for (int kk = 0; kk < 4; ++kk) {
        const int cc = kk * 2 + half;
        short8 aq[2], bq[2];
#pragma unroll
        for (int it = 0; it < 2; ++it) {
          const int r = it * 32 + ln;
          aq[it] = ld_frag8(sQ + r * 512 + kc * 64 + ((cc ^ ((r ^ (r >> 3)) & 7)) * 8));
        }
#pragma unroll
        for (int j2 = 0; j2 < 2; ++j2)
          bq[j2] = ld_frag8(Bg + (size_t)(j2 * 32 + ln) * DIM + kc * 64 + kk * 16 + half * 8);
#pragma unroll
        for (int it = 0; it < 2; ++it)
#pragma unroll
          for (int j2 = 0; j2 < 2; ++j2)
            acc_s[it][j2] = __builtin_amdgcn_mfma_f32_32x32x16_bf16(aq[it], bq[j2], acc_s[it][j2], 0, 0, 0);
      }
    }

    // p = exp(s^2 - 1) in-register (before the barrier, off the serialized path)
#pragma unroll
    for (int it = 0; it < 2; ++it)
#pragma unroll
      for (int j2 = 0; j2 < 2; ++j2)
#pragma unroll
        for (int r = 0; r < 16; ++r) {
          const float s = acc_s[it][j2][r];
          acc_s[it][j2][r] = __expf(__builtin_fmaf(s, s, -1.0f));
        }

    __syncthreads();   // all readers of previous sP (PV + row-sum) are done

    // write bf16 P into swizzled sP ; chunk = w, logical col = w*64 + j2*32 + ln
#pragma unroll
    for (int it = 0; it < 2; ++it)
#pragma unroll
      for (int j2 = 0; j2 < 2; ++j2) {
        const int csub = j2 * 4 + (ln >> 3);   // logical sub-granule within chunk
        const int coff = ln & 7;
#pragma unroll
        for (int r = 0; r < 16; ++r) {
          const int row = it * 32 + (r & 3) + 8 * (r >> 2) + 4 * half;
          const int sw  = (row ^ (row >> 3)) & 7;
          sP[row * 512 + w * 64 + ((csub ^ sw) * 8) + coff] = f32_bf16(acc_s[it][j2][r]);
        }
      }

    __syncthreads();   // sP ready

    // ---------- PV phase: per-wave d-slice [64 i][64 d] at d0 = w*64, K = 512 (this j-tile) --
    const unsigned short* Vg = xtb + (size_t)(w * 64) * SEQ + j0;
#pragma unroll
    for (int kc = 0; kc < 8; ++kc) {
#pragma unroll
      for (int kk = 0; kk < 4; ++kk) {
        const int cc = kk * 2 + half;
        short8 ap[2], bx[2];
#pragma unroll
        for (int it = 0; it < 2; ++it) {
          const int r = it * 32 + ln;
          ap[it] = ld_frag8(sP + r * 512 + kc * 64 + ((cc ^ ((r ^ (r >> 3)) & 7)) * 8));
        }
#pragma unroll
        for (int dt = 0; dt < 2; ++dt)
          bx[dt] = ld_frag8(Vg + (size_t)(dt * 32 + ln) * SEQ + kc * 64 + kk * 16 + half * 8);
#pragma unroll
        for (int it = 0; it < 2; ++it)
#pragma unroll
          for (int dt = 0; dt < 2; ++dt)
            acc_o[it][dt] = __builtin_amdgcn_mfma_f32_32x32x16_bf16(ap[it], bx[dt], acc_o[it][dt], 0, 0, 0);
      }
    }

    // fused row-sum of the exact bf16 P values (swizzle permutes within a row: sum invariant)
    {
      float s = 0.f;
      const unsigned short* rp = sP + lrow * 512;
#pragma unroll
      for (int q = 0; q < 8; ++q) {
        const uint4 v = *reinterpret_cast<const uint4*>(rp + (q * 8 + lseg) * 8);
        s += bf_lo(v.x) + bf_hi(v.x) + bf_lo(v.y) + bf_hi(v.y)
           + bf_lo(v.z) + bf_hi(v.z) + bf_lo(v.w) + bf_hi(v.w);
      }
      s += __shfl_xor(s, 1);
      s += __shfl_xor(s, 2);
      s += __shfl_xor(s, 4);
      if (lseg == 0) lsum += s;
    }
  }

  if (lseg == 0) sL[lrow] = lsum;
  __syncthreads();
  if (tid < 64) sL[tid] = 1.0f / sL[tid];
  __syncthreads();

  // epilogue: O / l, coalesced fp32 stores (32 consecutive floats per half-wave)
  float* outb = out + ((size_t)b * SEQ + i0) * DIM + w * 64;
#pragma unroll
  for (int it = 0; it < 2; ++it)
#pragma unroll
    for (int r = 0; r < 16; ++r) {
      const int row = it * 32 + (r & 3) + 8 * (r >> 2) + 4 * half;
      const float inv = sL[row];
#pragma unroll
      for (int dt = 0; dt < 2; ++dt)
        outb[(size_t)row * DIM + dt * 32 + ln] = acc_o[it][dt][r] * inv;
    }
}

extern "C" void kernel_launch(void* const* d_in, const int* in_sizes, int n_in,
                              void* d_out, int out_size, void* d_ws, size_t ws_size,
                              hipStream_t stream) {
  const float* x = (const float*)d_in[0];
  float* outp = (float*)d_out;

  unsigned short* xn = (unsigned short*)d_ws;                        // 16.78 MB
  unsigned short* xt = xn + (size_t)BATCH * SEQ * DIM;               // 16.78 MB

  prep_kernel <<<BATCH * (SEQ / 32), 256, 0, stream>>>(x, xn, xt);
  fused_kernel<<<BATCH * (SEQ / 64), 512, 0, stream>>>(xn, xt, outp);
}